// Round 8
// baseline (881.051 us; speedup 1.0000x reference)
//
#include <hip/hip_runtime.h>
#include <hip/hip_bf16.h>

#define NV 26
#define NS 1024
#define NC 256
#define NH 8
#define ND 32
#define NPAIR 66

typedef unsigned short u16;
typedef unsigned int u32;
typedef short short8_t __attribute__((ext_vector_type(8)));   // 8 bf16 MFMA frag
typedef float f32x4 __attribute__((ext_vector_type(4)));      // MFMA accumulator
typedef unsigned int u32x4 __attribute__((ext_vector_type(4)));

// ---------------- static routing tables (from _angle_select / _mha_index) ----------------
__constant__ int c_view_m[NV]  = {0,1,2,2,2,2,2,2,2,2,3,3,3,3,3,3,3,3,4,4,4,4,4,4,4,4};
__constant__ int c_view_nk[NV] = {4,4,4,3,4,3,4,3,4,3,4,4,4,4,4,4,4,4,4,3,4,3,4,3,4,3};
__constant__ int c_view_kv[NV][4] = {
  {0,1,2,3},      {4,5,6,7},      {8,10,16,17},   {9,11,18,-1},
  {8,10,12,19},   {11,13,20,-1},  {8,12,14,21},   {13,15,22,-1},
  {8,14,16,23},   {9,15,24,-1},   {25,34,40,41},  {26,33,35,42},
  {27,34,36,43},  {28,35,37,44},  {29,36,38,45},  {30,37,39,46},
  {31,38,40,47},  {32,33,39,48},  {49,50,59,65},  {51,58,60,-1},
  {49,52,59,61},  {53,60,62,-1},  {49,54,61,63},  {55,62,64,-1},
  {49,56,63,65},  {57,58,64,-1}
};
__constant__ int c_pair_m[NPAIR] = {
  0,0,0,0, 1,1,1,1,
  2,2,2,2,2,2,2,2,2,2,2,2,2,2,2,2,2,
  3,3,3,3,3,3,3,3,3,3,3,3,3,3,3,3,3,3,3,3,3,3,3,3,
  4,4,4,4,4,4,4,4,4,4,4,4,4,4,4,4,4
};
__constant__ int c_pair_j[NPAIR] = {
  18,20,22,24, 2,4,6,8,
  1,2,3,4,5,6,7,8,9,10,11,12,13,14,15,16,17,
  2,3,4,5,6,7,8,9,10,11,12,13,14,15,16,17,18,19,20,21,22,23,24,25,
  0,10,11,12,13,14,15,16,17,18,19,20,21,22,23,24,25
};

__device__ __forceinline__ float bf16_to_f32(u16 u) {
  return __uint_as_float(((u32)u) << 16);
}
__device__ __forceinline__ u16 f32_to_bf16(float f) {   // RNE
  u32 u = __float_as_uint(f);
  u32 r = (u + 0x7fffu + ((u >> 16) & 1u)) >> 16;
  return (u16)r;
}
__device__ __forceinline__ float ld_src(const void* p, size_t i, bool isf) {
  return isf ? ((const float*)p)[i] : bf16_to_f32(((const u16*)p)[i]);
}
// single-instruction packed f32x2 -> bf16x2 (RNE); guarantees no SW-RNE expansion
__device__ __forceinline__ u32 cvt_pk_bf16(float a, float b) {
  u32 r;
  asm("v_cvt_pk_bf16_f32 %0, %1, %2" : "=v"(r) : "v"(a), "v"(b));
  return r;
}
// dtype probe: fp32 tensors reinterpreted as bf16 halves blow past 1e6 almost surely
// over 64 samples (low halves have uniform-random exponent bits). Wave-uniform result.
__device__ __forceinline__ bool detect_isf(const u16* __restrict__ x) {
  float f = fabsf(bf16_to_f32(x[threadIdx.x & 63]));
  if (!(f < 3.0e38f)) f = 3.0e38f;
#pragma unroll
  for (int m = 1; m < 64; m <<= 1) f = fmaxf(f, __shfl_xor(f, m));
  return f > 1.0e6f;
}

// ------- prep_w: W -> bf16 (keep [o][c] layout = MFMA A-operand), biases -> fp32 -------
#define NW1 983040
#define NW2 327680
#define NB1 3840
#define NB2 1280
__global__ __launch_bounds__(256) void prep_w_kernel(const u16* __restrict__ xdet,
                                                     const void* __restrict__ w_qkv,
                                                     const void* __restrict__ w_out,
                                                     const void* __restrict__ b_qkv,
                                                     const void* __restrict__ b_out,
                                                     u16* __restrict__ Wqkvb, u16* __restrict__ Wob,
                                                     float* __restrict__ bq, float* __restrict__ bo) {
  bool isf = detect_isf(xdet);
  int i = blockIdx.x * 256 + threadIdx.x;
  if (i < NW1) Wqkvb[i] = f32_to_bf16(ld_src(w_qkv, i, isf));
  else if (i < NW1 + NW2) Wob[i - NW1] = f32_to_bf16(ld_src(w_out, i - NW1, isf));
  else if (i < NW1 + NW2 + NB1) bq[i - NW1 - NW2] = ld_src(b_qkv, i - NW1 - NW2, isf);
  else if (i < NW1 + NW2 + NB1 + NB2) bo[i - NW1 - NW2 - NB1] = ld_src(b_out, i - NW1 - NW2 - NB1, isf);
}

// ------- prep_x: x[bt][c][s] -> Xt[bt][s][c] bf16 (MFMA B-operand layout) -------
__global__ __launch_bounds__(256) void prep_x_kernel(const void* __restrict__ xin,
                                                     u16* __restrict__ Xt) {
  __shared__ float tile[32][33];
  bool isf = detect_isf((const u16*)xin);
  int bt = blockIdx.x;
  int s0 = blockIdx.y * 32, c0 = blockIdx.z * 32;
  int tid = threadIdx.x;
#pragma unroll
  for (int p = 0; p < 4; ++p) {
    int cl = (tid >> 5) + p * 8, sl = tid & 31;
    tile[cl][sl] = ld_src(xin, (size_t)(bt * NC + c0 + cl) * NS + s0 + sl, isf);
  }
  __syncthreads();
  int srow = tid >> 3, c4 = (tid & 7) * 4;
  ushort4 v;
  v.x = f32_to_bf16(tile[c4 + 0][srow]);
  v.y = f32_to_bf16(tile[c4 + 1][srow]);
  v.z = f32_to_bf16(tile[c4 + 2][srow]);
  v.w = f32_to_bf16(tile[c4 + 3][srow]);
  *(ushort4*)&Xt[(size_t)(bt * NS + s0 + srow) * NC + c0 + c4] = v;
}

// ------- LDS-staged GEMM tile: 128 o x 128 s, K=256, reg-prefetch pipeline -------
__device__ __forceinline__ void gemm128(const u16* __restrict__ A, const u16* __restrict__ B,
                                        u16* As, u16* Bs, f32x4 acc[4][4],
                                        int wo, int ws, int lm, int g, int tid) {
#pragma unroll
  for (int i = 0; i < 4; ++i)
#pragma unroll
    for (int j = 0; j < 4; ++j)
#pragma unroll
      for (int r = 0; r < 4; ++r) acc[i][j][r] = 0.f;
  int c0i = tid, c1i = tid + 256;
  const u16* a0p = A + (c0i >> 2) * NC + (c0i & 3) * 8;
  const u16* a1p = A + (c1i >> 2) * NC + (c1i & 3) * 8;
  const u16* b0p = B + (c0i >> 2) * NC + (c0i & 3) * 8;
  const u16* b1p = B + (c1i >> 2) * NC + (c1i & 3) * 8;
  uint4 ra0 = *(const uint4*)(a0p);
  uint4 ra1 = *(const uint4*)(a1p);
  uint4 rb0 = *(const uint4*)(b0p);
  uint4 rb1 = *(const uint4*)(b1p);
  const u16* arow = As + (wo * 64 + lm) * 32 + g * 8;
  const u16* brow = Bs + (ws * 64 + lm) * 32 + g * 8;
#pragma unroll
  for (int k0 = 0; k0 < NC; k0 += 32) {
    __syncthreads();
    *(uint4*)&As[c0i * 8] = ra0;
    *(uint4*)&As[c1i * 8] = ra1;
    *(uint4*)&Bs[c0i * 8] = rb0;
    *(uint4*)&Bs[c1i * 8] = rb1;
    if (k0 + 32 < NC) {
      ra0 = *(const uint4*)(a0p + k0 + 32);
      ra1 = *(const uint4*)(a1p + k0 + 32);
      rb0 = *(const uint4*)(b0p + k0 + 32);
      rb1 = *(const uint4*)(b1p + k0 + 32);
    }
    __syncthreads();
    short8_t af[4], bf[4];
#pragma unroll
    for (int i = 0; i < 4; ++i) af[i] = *(const short8_t*)(arow + i * 16 * 32);
#pragma unroll
    for (int j = 0; j < 4; ++j) bf[j] = *(const short8_t*)(brow + j * 16 * 32);
#pragma unroll
    for (int i = 0; i < 4; ++i)
#pragma unroll
      for (int j = 0; j < 4; ++j)
        acc[i][j] = __builtin_amdgcn_mfma_f32_16x16x32_bf16(af[i], bf[j], acc[i][j], 0, 0, 0);
  }
}

// ------- fused QKV projection: q jobs (blocks 0..831) then kv jobs (832..5055) -------
// K written [pair][h][key][dim]; V written TRANSPOSED [pair][h][dim][key] so the
// attention kernel can read V^T fragments straight from global (no LDS staging).
__global__ __launch_bounds__(256, 3) void qkvproj_kernel(const u16* __restrict__ Xt,
                                                         const u16* __restrict__ Wqkvb,
                                                         const float* __restrict__ bq,
                                                         u16* __restrict__ Qb,
                                                         u16* __restrict__ Kb,
                                                         u16* __restrict__ Vb) {
  __shared__ __align__(16) u16 As[128 * 32];
  __shared__ __align__(16) u16 Bs[128 * 32];
  int bid = blockIdx.x;
  int tid = threadIdx.x;
  int wave = tid >> 6, lane = tid & 63, lm = lane & 15, g = lane >> 4;
  int wo = wave >> 1, ws = wave & 1;

  int obase, s0, m, src_bt;
  u16* dst; int dslot; float sc; bool isV = false;
  if (bid < 832) {
    int bt = bid >> 4, rem = bid & 15;
    obase = (rem & 1) * 128; s0 = (rem >> 1) * 128;
    m = c_view_m[bt % NV]; src_bt = bt;
    dst = Qb; dslot = bt; sc = 0.25505653862161186f;
  } else {
    int jb = bid - 832;
    int pb = jb >> 5, rem = jb & 31;
    int ot = rem & 3; s0 = (rem >> 2) * 128;
    obase = 256 + ot * 128;
    m = c_pair_m[pb >> 1]; src_bt = (pb & 1) * NV + c_pair_j[pb >> 1];
    dst = (ot < 2) ? Kb : Vb; dslot = pb; sc = 1.0f;
    isV = (ot >= 2);
  }
  f32x4 acc[4][4];
  gemm128(Wqkvb + (size_t)(m * 768 + obase) * NC,
          Xt + ((size_t)src_bt * NS + s0) * NC, As, Bs, acc, wo, ws, lm, g, tid);
  int osub = (obase < 256) ? 0 : ((obase < 512) ? 256 : 512);
#pragma unroll
  for (int i = 0; i < 4; ++i) {
    int o_r0 = obase + wo * 64 + i * 16 + 4 * g;
    float4 bias = *(const float4*)&bq[m * 768 + o_r0];
    int oloc = o_r0 - osub;
    int h = oloc >> 5, d0 = oloc & 31;
#pragma unroll
    for (int j = 0; j < 4; ++j) {
      int s = s0 + ws * 64 + j * 16 + lm;
      f32x4 c = acc[i][j];
      ushort4 v;
      v.x = f32_to_bf16((c[0] + bias.x) * sc);
      v.y = f32_to_bf16((c[1] + bias.y) * sc);
      v.z = f32_to_bf16((c[2] + bias.z) * sc);
      v.w = f32_to_bf16((c[3] + bias.w) * sc);
      if (isV) {
        // V^T layout: [pair][h][d][key]; 4 consecutive dims -> 4 strided u16 stores
        u16* vt = dst + ((size_t)(dslot * NH + h) * ND + d0) * NS + s;
        vt[0]      = v.x;
        vt[NS]     = v.y;
        vt[2 * NS] = v.z;
        vt[3 * NS] = v.w;
      } else {
        *(ushort4*)&dst[((size_t)(dslot * NH + h) * NS + s) * ND + d0] = v;
      }
    }
  }
}

// ---------------- MFMA flash attention: in-register softmax/transpose + K/V reg prefetch -------
// Zero LDS, zero barriers. XCD-aware grid swizzle (R5: FETCH 406->85MB -> K/V are L2 hits).
// R8: restore the R5 ping-pong register prefetch ON TOP of the R6 cvt_pk asm — now that K/V
// loads are L2 hits (~few-hundred cy), issuing chunk cc+1's 8 loads before chunk cc's compute
// (~1-2k cy window) fully hides the per-chunk vmcnt stall that R6 exposed at point-of-use.
// setprio fences around the permlane-asm compute region are kept: every passing version had
// them, and R7 (which removed them + changed geometry) corrupted results (rule-18 class).
__global__ __launch_bounds__(256, 4) void attn_kernel(const u16* __restrict__ Qb,
                                                      const u16* __restrict__ Kb,
                                                      const u16* __restrict__ Vb,
                                                      u16* __restrict__ Ot) {
  int gid = blockIdx.x;
  int grp = (gid >> 5) * 8 + (gid & 7);   // bt*8 + h
  int z = (gid >> 3) & 3;
  int bt = grp >> 3;
  int h = grp & 7;
  int view = bt % NV;
  int b = bt / NV;
  int tid = threadIdx.x;
  int wave = tid >> 6, lane = tid & 63;
  int lm = lane & 15, g = lane >> 4;
  int sbase = z * 256 + wave * 64;
  int nk = c_view_nk[view];

  short8_t qf[4];
  {
    const u16* qrow = Qb + ((size_t)(bt * NH + h) * NS + sbase) * ND;
#pragma unroll
    for (int qt = 0; qt < 4; ++qt)
      qf[qt] = *(const short8_t*)(qrow + (qt * 16 + lm) * ND + g * 8);
  }
  f32x4 accq[4][2];
  f32x4 acc_l[4];
#pragma unroll
  for (int qt = 0; qt < 4; ++qt) {
#pragma unroll
    for (int r = 0; r < 4; ++r) { accq[qt][0][r] = 0.f; accq[qt][1][r] = 0.f; acc_l[qt][r] = 0.f; }
  }
  short8_t ones;
#pragma unroll
  for (int e = 0; e < 8; ++e) ones[e] = (short)0x3F80;   // bf16 1.0

  int tot = nk * 16;

  // loop-invariant lane offsets (u16 units)
  const int kvo  = lm * ND + g * 8;          // K: row lm, dwords g*8; kt via +kt*16*ND
  const int vvo0 = lm * NS + g * 8;          // V^T nt=0
  const int vvo1 = (16 + lm) * NS + g * 8;   // V^T nt=1

  // segment base for pair index nn (wave-uniform)
  auto seg_off = [&](int nn) -> size_t {
    int kvp = c_view_kv[view][nn];
    return (size_t)((kvp * 2 + b) * NH + h) * NS * ND;
  };

  short8_t KA[4], VA[4], KB[4], VB[4];

#define LOADK(DST, KP)                                                        \
  {                                                                           \
    _Pragma("unroll")                                                         \
    for (int kt = 0; kt < 4; ++kt)                                            \
      DST[kt] = *(const short8_t*)((KP) + kt * 16 * ND + kvo);                \
  }
#define LOADV(DST, VP)                                                        \
  {                                                                           \
    DST[0] = *(const short8_t*)((VP) + vvo0);                                 \
    DST[1] = *(const short8_t*)((VP) + vvo0 + 32);                            \
    DST[2] = *(const short8_t*)((VP) + vvo1);                                 \
    DST[3] = *(const short8_t*)((VP) + vvo1 + 32);                            \
  }

  // compute one 64-key chunk from register fragments K[4], V[4(nt*2+k2)]
  auto compute = [&](const short8_t (&K)[4], const short8_t (&V)[4]) {
    __builtin_amdgcn_s_setprio(1);
#pragma unroll
    for (int qt = 0; qt < 4; ++qt) {
      f32x4 z4 = {0.f, 0.f, 0.f, 0.f};
      f32x4 sv[4];
#pragma unroll
      for (int kt = 0; kt < 4; ++kt)
        sv[kt] = __builtin_amdgcn_mfma_f32_16x16x32_bf16(K[kt], qf[qt], z4, 0, 0, 0);
      u32 w[4][2];
#pragma unroll
      for (int kt = 0; kt < 4; ++kt) {
        float p0 = __builtin_amdgcn_exp2f(sv[kt][0]);
        float p1 = __builtin_amdgcn_exp2f(sv[kt][1]);
        float p2 = __builtin_amdgcn_exp2f(sv[kt][2]);
        float p3 = __builtin_amdgcn_exp2f(sv[kt][3]);
        w[kt][0] = cvt_pk_bf16(p0, p1);
        w[kt][1] = cvt_pk_bf16(p2, p3);
      }
      // in-register transpose: (kt0 <-> lane bit5), then (lane bit5 old <-> lane bit4)
      u32 pa[2][4];
#pragma unroll
      for (int kt1 = 0; kt1 < 2; ++kt1) {
#pragma unroll
        for (int hh = 0; hh < 2; ++hh) {
          u32 X = w[2 * kt1][hh], Y = w[2 * kt1 + 1][hh];
          asm("v_permlane32_swap_b32 %0, %1" : "+v"(X), "+v"(Y));
          asm("v_permlane16_swap_b32 %0, %1" : "+v"(X), "+v"(Y));
          pa[kt1][hh] = X;       // j1=0 -> word j=hh
          pa[kt1][2 + hh] = Y;   // j1=1 -> word j=2+hh
        }
      }
      u32x4 a0 = {pa[0][0], pa[0][1], pa[0][2], pa[0][3]};
      u32x4 a1 = {pa[1][0], pa[1][1], pa[1][2], pa[1][3]};
      short8_t pf0 = __builtin_bit_cast(short8_t, a0);   // keys 0..31 of chunk
      short8_t pf1 = __builtin_bit_cast(short8_t, a1);   // keys 32..63 of chunk
      accq[qt][0] = __builtin_amdgcn_mfma_f32_16x16x32_bf16(pf0, V[0], accq[qt][0], 0, 0, 0);
      accq[qt][0] = __builtin_amdgcn_mfma_f32_16x16x32_bf16(pf1, V[1], accq[qt][0], 0, 0, 0);
      accq[qt][1] = __builtin_amdgcn_mfma_f32_16x16x32_bf16(pf0, V[2], accq[qt][1], 0, 0, 0);
      accq[qt][1] = __builtin_amdgcn_mfma_f32_16x16x32_bf16(pf1, V[3], accq[qt][1], 0, 0, 0);
      acc_l[qt]   = __builtin_amdgcn_mfma_f32_16x16x32_bf16(pf0, ones, acc_l[qt], 0, 0, 0);
      acc_l[qt]   = __builtin_amdgcn_mfma_f32_16x16x32_bf16(pf1, ones, acc_l[qt], 0, 0, 0);
    }
    __builtin_amdgcn_s_setprio(0);
  };

  // prologue: chunk 0 -> A
  const u16* kp = Kb + seg_off(0);
  const u16* vp = Vb + seg_off(0);
  LOADK(KA, kp); LOADV(VA, vp);

  for (int cc = 0; cc < tot; cc += 2) {
    // pointers for chunk cc+1 (always valid: tot is a multiple of 16 >= 16, cc+1 < tot)
    const u16 *kp1, *vp1;
    if (((cc + 1) & 15) == 0) {
      size_t o = seg_off((cc + 1) >> 4);
      kp1 = Kb + o; vp1 = Vb + o;
    } else {
      kp1 = kp + 64 * ND; vp1 = vp + 64;
    }
    LOADK(KB, kp1); LOADV(VB, vp1);
    compute(KA, VA);

    // pointers for chunk cc+2 (guard table lookup at cc+2 == tot)
    const u16 *kp2, *vp2;
    if (((cc + 2) & 15) == 0) {
      if (cc + 2 < tot) { size_t o = seg_off((cc + 2) >> 4); kp2 = Kb + o; vp2 = Vb + o; }
      else { kp2 = kp1; vp2 = vp1; }
    } else {
      kp2 = kp1 + 64 * ND; vp2 = vp1 + 64;
    }
    if (cc + 2 < tot) { LOADK(KA, kp2); LOADV(VA, vp2); }
    compute(KB, VB);
    kp = kp2; vp = vp2;
  }
#undef LOADK
#undef LOADV

  // epilogue: acc_l[qt][r] already holds l for query 4g+r (broadcast over lm)
#pragma unroll
  for (int qt = 0; qt < 4; ++qt) {
#pragma unroll
    for (int r = 0; r < 4; ++r) {
      float inv = __builtin_amdgcn_rcpf(acc_l[qt][r]);
      int s = sbase + qt * 16 + 4 * g + r;
      u16* op = Ot + (size_t)(bt * NS + s) * NC + h * 32 + lm;
      op[0]  = f32_to_bf16(accq[qt][0][r] * inv);
      op[16] = f32_to_bf16(accq[qt][1][r] * inv);
    }
  }
}

// ------- output projection (LDS GEMM): out[bt][o][s] = Wo[m]·O^T + bo -------
__global__ __launch_bounds__(256, 3) void oproj_kernel(const u16* __restrict__ xdet,
                                                       const u16* __restrict__ Ot,
                                                       const u16* __restrict__ Wob,
                                                       const float* __restrict__ bo,
                                                       void* __restrict__ out) {
  __shared__ __align__(16) u16 As[128 * 32];
  __shared__ __align__(16) u16 Bs[128 * 32];
  bool isf = detect_isf(xdet);
  int bid = blockIdx.x;
  int bt = bid >> 4, rem = bid & 15;
  int obase = (rem & 1) * 128, s0 = (rem >> 1) * 128;
  int m = c_view_m[bt % NV];
  int tid = threadIdx.x;
  int wave = tid >> 6, lane = tid & 63, lm = lane & 15, g = lane >> 4;
  int wo = wave >> 1, ws = wave & 1;
  f32x4 acc[4][4];
  gemm128(Wob + (size_t)(m * NC + obase) * NC,
          Ot + ((size_t)bt * NS + s0) * NC, As, Bs, acc, wo, ws, lm, g, tid);
#pragma unroll
  for (int i = 0; i < 4; ++i) {
    int o_r0 = obase + wo * 64 + i * 16 + 4 * g;
    float4 bias = *(const float4*)&bo[m * NC + o_r0];
#pragma unroll
    for (int j = 0; j < 4; ++j) {
      int s = s0 + ws * 64 + j * 16 + lm;
      f32x4 c = acc[i][j];
      size_t base = (size_t)(bt * NC + o_r0) * NS + s;
      float v0 = c[0] + bias.x, v1 = c[1] + bias.y, v2 = c[2] + bias.z, v3 = c[3] + bias.w;
      if (isf) {
        float* fo = (float*)out;
        fo[base] = v0; fo[base + NS] = v1; fo[base + 2 * NS] = v2; fo[base + 3 * NS] = v3;
      } else {
        u16* ho = (u16*)out;
        ho[base] = f32_to_bf16(v0); ho[base + NS] = f32_to_bf16(v1);
        ho[base + 2 * NS] = f32_to_bf16(v2); ho[base + 3 * NS] = f32_to_bf16(v3);
      }
    }
  }
}

// ---------------- workspace layout (bytes) ----------------
// 0:        bq fp32 (15360)       -> 15360
// 15360:    bo fp32 (5120)        -> 20480
// 20480:    Wqkvb bf16 (1966080)  -> 1986560
// 1986560:  Wob bf16 (655360)     -> 2641920
// 2641920:  Xt bf16 (27262976)    -> 29904896
// 29904896: Qb bf16 (27262976)    -> 57167872
// 57167872: Kb bf16 (69206016)    -> 126373888   [pair][h][key][dim]
// 126373888:Vb bf16 (69206016)    -> 195579904   [pair][h][dim][key]  (pre-transposed)
// 195579904:Ot bf16 (27262976)    -> 222842880

extern "C" void kernel_launch(void* const* d_in, const int* in_sizes, int n_in,
                              void* d_out, int out_size, void* d_ws, size_t ws_size,
                              hipStream_t stream) {
  (void)in_sizes; (void)n_in; (void)out_size;
  const void* x     = d_in[0];
  const void* w_qkv = d_in[1];
  const void* b_qkv = d_in[2];
  const void* w_out = d_in[3];
  const void* b_out = d_in[4];

  if (ws_size < 222842880ull) return;

  char* wsb = (char*)d_ws;
  float* bq    = (float*)(wsb + 0);
  float* bo    = (float*)(wsb + 15360);
  u16*   Wqkvb = (u16*)(wsb + 20480);
  u16*   Wob   = (u16*)(wsb + 1986560);
  u16*   Xt    = (u16*)(wsb + 2641920);
  u16*   Qb    = (u16*)(wsb + 29904896);
  u16*   Kb    = (u16*)(wsb + 57167872);
  u16*   Vb    = (u16*)(wsb + 126373888);
  u16*   Ot    = (u16*)(wsb + 195579904);

  prep_w_kernel<<<5140, 256, 0, stream>>>((const u16*)x, w_qkv, w_out, b_qkv, b_out,
                                          Wqkvb, Wob, bq, bo);
  prep_x_kernel<<<dim3(52, 32, 8), 256, 0, stream>>>(x, Xt);
  qkvproj_kernel<<<5056, 256, 0, stream>>>(Xt, Wqkvb, bq, Qb, Kb, Vb);
  attn_kernel<<<1664, 256, 0, stream>>>(Qb, Kb, Vb, Ot);
  oproj_kernel<<<832, 256, 0, stream>>>((const u16*)x, Ot, Wob, bo, d_out);
}

// Round 9
// 550.097 us; speedup vs baseline: 1.6016x; 1.6016x over previous
//
#include <hip/hip_runtime.h>
#include <hip/hip_bf16.h>

#define NV 26
#define NS 1024
#define NC 256
#define NH 8
#define ND 32
#define NPAIR 66

typedef unsigned short u16;
typedef unsigned int u32;
typedef short short8_t __attribute__((ext_vector_type(8)));   // 8 bf16 MFMA frag
typedef float f32x4 __attribute__((ext_vector_type(4)));      // MFMA accumulator
typedef unsigned int u32x4 __attribute__((ext_vector_type(4)));

// ---------------- static routing tables (from _angle_select / _mha_index) ----------------
__constant__ int c_view_m[NV]  = {0,1,2,2,2,2,2,2,2,2,3,3,3,3,3,3,3,3,4,4,4,4,4,4,4,4};
__constant__ int c_view_nk[NV] = {4,4,4,3,4,3,4,3,4,3,4,4,4,4,4,4,4,4,4,3,4,3,4,3,4,3};
__constant__ int c_view_kv[NV][4] = {
  {0,1,2,3},      {4,5,6,7},      {8,10,16,17},   {9,11,18,-1},
  {8,10,12,19},   {11,13,20,-1},  {8,12,14,21},   {13,15,22,-1},
  {8,14,16,23},   {9,15,24,-1},   {25,34,40,41},  {26,33,35,42},
  {27,34,36,43},  {28,35,37,44},  {29,36,38,45},  {30,37,39,46},
  {31,38,40,47},  {32,33,39,48},  {49,50,59,65},  {51,58,60,-1},
  {49,52,59,61},  {53,60,62,-1},  {49,54,61,63},  {55,62,64,-1},
  {49,56,63,65},  {57,58,64,-1}
};
__constant__ int c_pair_m[NPAIR] = {
  0,0,0,0, 1,1,1,1,
  2,2,2,2,2,2,2,2,2,2,2,2,2,2,2,2,2,
  3,3,3,3,3,3,3,3,3,3,3,3,3,3,3,3,3,3,3,3,3,3,3,3,
  4,4,4,4,4,4,4,4,4,4,4,4,4,4,4,4,4
};
__constant__ int c_pair_j[NPAIR] = {
  18,20,22,24, 2,4,6,8,
  1,2,3,4,5,6,7,8,9,10,11,12,13,14,15,16,17,
  2,3,4,5,6,7,8,9,10,11,12,13,14,15,16,17,18,19,20,21,22,23,24,25,
  0,10,11,12,13,14,15,16,17,18,19,20,21,22,23,24,25
};

__device__ __forceinline__ float bf16_to_f32(u16 u) {
  return __uint_as_float(((u32)u) << 16);
}
__device__ __forceinline__ u16 f32_to_bf16(float f) {   // RNE
  u32 u = __float_as_uint(f);
  u32 r = (u + 0x7fffu + ((u >> 16) & 1u)) >> 16;
  return (u16)r;
}
__device__ __forceinline__ float ld_src(const void* p, size_t i, bool isf) {
  return isf ? ((const float*)p)[i] : bf16_to_f32(((const u16*)p)[i]);
}
// single-instruction packed f32x2 -> bf16x2 (RNE); guarantees no SW-RNE expansion
__device__ __forceinline__ u32 cvt_pk_bf16(float a, float b) {
  u32 r;
  asm("v_cvt_pk_bf16_f32 %0, %1, %2" : "=v"(r) : "v"(a), "v"(b));
  return r;
}
// dtype probe: fp32 tensors reinterpreted as bf16 halves blow past 1e6 almost surely
// over 64 samples (low halves have uniform-random exponent bits). Wave-uniform result.
__device__ __forceinline__ bool detect_isf(const u16* __restrict__ x) {
  float f = fabsf(bf16_to_f32(x[threadIdx.x & 63]));
  if (!(f < 3.0e38f)) f = 3.0e38f;
#pragma unroll
  for (int m = 1; m < 64; m <<= 1) f = fmaxf(f, __shfl_xor(f, m));
  return f > 1.0e6f;
}

// ------- prep_w: W -> bf16 (keep [o][c] layout = MFMA A-operand), biases -> fp32 -------
#define NW1 983040
#define NW2 327680
#define NB1 3840
#define NB2 1280
__global__ __launch_bounds__(256) void prep_w_kernel(const u16* __restrict__ xdet,
                                                     const void* __restrict__ w_qkv,
                                                     const void* __restrict__ w_out,
                                                     const void* __restrict__ b_qkv,
                                                     const void* __restrict__ b_out,
                                                     u16* __restrict__ Wqkvb, u16* __restrict__ Wob,
                                                     float* __restrict__ bq, float* __restrict__ bo) {
  bool isf = detect_isf(xdet);
  int i = blockIdx.x * 256 + threadIdx.x;
  if (i < NW1) Wqkvb[i] = f32_to_bf16(ld_src(w_qkv, i, isf));
  else if (i < NW1 + NW2) Wob[i - NW1] = f32_to_bf16(ld_src(w_out, i - NW1, isf));
  else if (i < NW1 + NW2 + NB1) bq[i - NW1 - NW2] = ld_src(b_qkv, i - NW1 - NW2, isf);
  else if (i < NW1 + NW2 + NB1 + NB2) bo[i - NW1 - NW2 - NB1] = ld_src(b_out, i - NW1 - NW2 - NB1, isf);
}

// ------- prep_x: x[bt][c][s] -> Xt[bt][s][c] bf16 (MFMA B-operand layout) -------
__global__ __launch_bounds__(256) void prep_x_kernel(const void* __restrict__ xin,
                                                     u16* __restrict__ Xt) {
  __shared__ float tile[32][33];
  bool isf = detect_isf((const u16*)xin);
  int bt = blockIdx.x;
  int s0 = blockIdx.y * 32, c0 = blockIdx.z * 32;
  int tid = threadIdx.x;
#pragma unroll
  for (int p = 0; p < 4; ++p) {
    int cl = (tid >> 5) + p * 8, sl = tid & 31;
    tile[cl][sl] = ld_src(xin, (size_t)(bt * NC + c0 + cl) * NS + s0 + sl, isf);
  }
  __syncthreads();
  int srow = tid >> 3, c4 = (tid & 7) * 4;
  ushort4 v;
  v.x = f32_to_bf16(tile[c4 + 0][srow]);
  v.y = f32_to_bf16(tile[c4 + 1][srow]);
  v.z = f32_to_bf16(tile[c4 + 2][srow]);
  v.w = f32_to_bf16(tile[c4 + 3][srow]);
  *(ushort4*)&Xt[(size_t)(bt * NS + s0 + srow) * NC + c0 + c4] = v;
}

// ------- LDS-staged GEMM tile: 128 o x 128 s, K=256, reg-prefetch pipeline -------
__device__ __forceinline__ void gemm128(const u16* __restrict__ A, const u16* __restrict__ B,
                                        u16* As, u16* Bs, f32x4 acc[4][4],
                                        int wo, int ws, int lm, int g, int tid) {
#pragma unroll
  for (int i = 0; i < 4; ++i)
#pragma unroll
    for (int j = 0; j < 4; ++j)
#pragma unroll
      for (int r = 0; r < 4; ++r) acc[i][j][r] = 0.f;
  int c0i = tid, c1i = tid + 256;
  const u16* a0p = A + (c0i >> 2) * NC + (c0i & 3) * 8;
  const u16* a1p = A + (c1i >> 2) * NC + (c1i & 3) * 8;
  const u16* b0p = B + (c0i >> 2) * NC + (c0i & 3) * 8;
  const u16* b1p = B + (c1i >> 2) * NC + (c1i & 3) * 8;
  uint4 ra0 = *(const uint4*)(a0p);
  uint4 ra1 = *(const uint4*)(a1p);
  uint4 rb0 = *(const uint4*)(b0p);
  uint4 rb1 = *(const uint4*)(b1p);
  const u16* arow = As + (wo * 64 + lm) * 32 + g * 8;
  const u16* brow = Bs + (ws * 64 + lm) * 32 + g * 8;
#pragma unroll
  for (int k0 = 0; k0 < NC; k0 += 32) {
    __syncthreads();
    *(uint4*)&As[c0i * 8] = ra0;
    *(uint4*)&As[c1i * 8] = ra1;
    *(uint4*)&Bs[c0i * 8] = rb0;
    *(uint4*)&Bs[c1i * 8] = rb1;
    if (k0 + 32 < NC) {
      ra0 = *(const uint4*)(a0p + k0 + 32);
      ra1 = *(const uint4*)(a1p + k0 + 32);
      rb0 = *(const uint4*)(b0p + k0 + 32);
      rb1 = *(const uint4*)(b1p + k0 + 32);
    }
    __syncthreads();
    short8_t af[4], bf[4];
#pragma unroll
    for (int i = 0; i < 4; ++i) af[i] = *(const short8_t*)(arow + i * 16 * 32);
#pragma unroll
    for (int j = 0; j < 4; ++j) bf[j] = *(const short8_t*)(brow + j * 16 * 32);
#pragma unroll
    for (int i = 0; i < 4; ++i)
#pragma unroll
      for (int j = 0; j < 4; ++j)
        acc[i][j] = __builtin_amdgcn_mfma_f32_16x16x32_bf16(af[i], bf[j], acc[i][j], 0, 0, 0);
  }
}

// ------- fused QKV projection: q jobs (blocks 0..831) then kv jobs (832..5055) -------
// K written [pair][h][key][dim]; V written TRANSPOSED [pair][h][dim][key] so the
// attention kernel can read V^T fragments straight from global (no LDS staging).
__global__ __launch_bounds__(256, 3) void qkvproj_kernel(const u16* __restrict__ Xt,
                                                         const u16* __restrict__ Wqkvb,
                                                         const float* __restrict__ bq,
                                                         u16* __restrict__ Qb,
                                                         u16* __restrict__ Kb,
                                                         u16* __restrict__ Vb) {
  __shared__ __align__(16) u16 As[128 * 32];
  __shared__ __align__(16) u16 Bs[128 * 32];
  int bid = blockIdx.x;
  int tid = threadIdx.x;
  int wave = tid >> 6, lane = tid & 63, lm = lane & 15, g = lane >> 4;
  int wo = wave >> 1, ws = wave & 1;

  int obase, s0, m, src_bt;
  u16* dst; int dslot; float sc; bool isV = false;
  if (bid < 832) {
    int bt = bid >> 4, rem = bid & 15;
    obase = (rem & 1) * 128; s0 = (rem >> 1) * 128;
    m = c_view_m[bt % NV]; src_bt = bt;
    dst = Qb; dslot = bt; sc = 0.25505653862161186f;
  } else {
    int jb = bid - 832;
    int pb = jb >> 5, rem = jb & 31;
    int ot = rem & 3; s0 = (rem >> 2) * 128;
    obase = 256 + ot * 128;
    m = c_pair_m[pb >> 1]; src_bt = (pb & 1) * NV + c_pair_j[pb >> 1];
    dst = (ot < 2) ? Kb : Vb; dslot = pb; sc = 1.0f;
    isV = (ot >= 2);
  }
  f32x4 acc[4][4];
  gemm128(Wqkvb + (size_t)(m * 768 + obase) * NC,
          Xt + ((size_t)src_bt * NS + s0) * NC, As, Bs, acc, wo, ws, lm, g, tid);
  int osub = (obase < 256) ? 0 : ((obase < 512) ? 256 : 512);
#pragma unroll
  for (int i = 0; i < 4; ++i) {
    int o_r0 = obase + wo * 64 + i * 16 + 4 * g;
    float4 bias = *(const float4*)&bq[m * 768 + o_r0];
    int oloc = o_r0 - osub;
    int h = oloc >> 5, d0 = oloc & 31;
#pragma unroll
    for (int j = 0; j < 4; ++j) {
      int s = s0 + ws * 64 + j * 16 + lm;
      f32x4 c = acc[i][j];
      ushort4 v;
      v.x = f32_to_bf16((c[0] + bias.x) * sc);
      v.y = f32_to_bf16((c[1] + bias.y) * sc);
      v.z = f32_to_bf16((c[2] + bias.z) * sc);
      v.w = f32_to_bf16((c[3] + bias.w) * sc);
      if (isV) {
        // V^T layout: [pair][h][d][key]; 4 consecutive dims -> 4 strided u16 stores
        u16* vt = dst + ((size_t)(dslot * NH + h) * ND + d0) * NS + s;
        vt[0]      = v.x;
        vt[NS]     = v.y;
        vt[2 * NS] = v.z;
        vt[3 * NS] = v.w;
      } else {
        *(ushort4*)&dst[((size_t)(dslot * NH + h) * NS + s) * ND + d0] = v;
      }
    }
  }
}

// ---------------- MFMA flash attention: in-register softmax/transpose + K/V reg prefetch -------
// Zero LDS, zero barriers. XCD-aware grid swizzle (R5: FETCH 406->85MB -> K/V are L2 hits).
// R9 = R8 with __launch_bounds__(256,3): R8's (256,4) capped VGPR at 128 and the allocator
// spilled the ping-pong K/V buffers to scratch (WRITE_SIZE 26MB -> 1.3GB). R5 proved this
// exact loop structure is spill-free at (256,3) (VGPR 80). cvt_pk asm kept from R6 (-14% VALU).
// setprio fences around the permlane-asm compute region are kept (R7 removal corrupted).
__global__ __launch_bounds__(256, 3) void attn_kernel(const u16* __restrict__ Qb,
                                                      const u16* __restrict__ Kb,
                                                      const u16* __restrict__ Vb,
                                                      u16* __restrict__ Ot) {
  int gid = blockIdx.x;
  int grp = (gid >> 5) * 8 + (gid & 7);   // bt*8 + h
  int z = (gid >> 3) & 3;
  int bt = grp >> 3;
  int h = grp & 7;
  int view = bt % NV;
  int b = bt / NV;
  int tid = threadIdx.x;
  int wave = tid >> 6, lane = tid & 63;
  int lm = lane & 15, g = lane >> 4;
  int sbase = z * 256 + wave * 64;
  int nk = c_view_nk[view];

  short8_t qf[4];
  {
    const u16* qrow = Qb + ((size_t)(bt * NH + h) * NS + sbase) * ND;
#pragma unroll
    for (int qt = 0; qt < 4; ++qt)
      qf[qt] = *(const short8_t*)(qrow + (qt * 16 + lm) * ND + g * 8);
  }
  f32x4 accq[4][2];
  f32x4 acc_l[4];
#pragma unroll
  for (int qt = 0; qt < 4; ++qt) {
#pragma unroll
    for (int r = 0; r < 4; ++r) { accq[qt][0][r] = 0.f; accq[qt][1][r] = 0.f; acc_l[qt][r] = 0.f; }
  }
  short8_t ones;
#pragma unroll
  for (int e = 0; e < 8; ++e) ones[e] = (short)0x3F80;   // bf16 1.0

  int tot = nk * 16;

  // loop-invariant lane offsets (u16 units)
  const int kvo  = lm * ND + g * 8;          // K: row lm, dwords g*8; kt via +kt*16*ND
  const int vvo0 = lm * NS + g * 8;          // V^T nt=0
  const int vvo1 = (16 + lm) * NS + g * 8;   // V^T nt=1

  // segment base for pair index nn (wave-uniform)
  auto seg_off = [&](int nn) -> size_t {
    int kvp = c_view_kv[view][nn];
    return (size_t)((kvp * 2 + b) * NH + h) * NS * ND;
  };

  short8_t KA[4], VA[4], KB[4], VB[4];

#define LOADK(DST, KP)                                                        \
  {                                                                           \
    _Pragma("unroll")                                                         \
    for (int kt = 0; kt < 4; ++kt)                                            \
      DST[kt] = *(const short8_t*)((KP) + kt * 16 * ND + kvo);                \
  }
#define LOADV(DST, VP)                                                        \
  {                                                                           \
    DST[0] = *(const short8_t*)((VP) + vvo0);                                 \
    DST[1] = *(const short8_t*)((VP) + vvo0 + 32);                            \
    DST[2] = *(const short8_t*)((VP) + vvo1);                                 \
    DST[3] = *(const short8_t*)((VP) + vvo1 + 32);                            \
  }

  // compute one 64-key chunk from register fragments K[4], V[4(nt*2+k2)]
  auto compute = [&](const short8_t (&K)[4], const short8_t (&V)[4]) {
    __builtin_amdgcn_s_setprio(1);
#pragma unroll
    for (int qt = 0; qt < 4; ++qt) {
      f32x4 z4 = {0.f, 0.f, 0.f, 0.f};
      f32x4 sv[4];
#pragma unroll
      for (int kt = 0; kt < 4; ++kt)
        sv[kt] = __builtin_amdgcn_mfma_f32_16x16x32_bf16(K[kt], qf[qt], z4, 0, 0, 0);
      u32 w[4][2];
#pragma unroll
      for (int kt = 0; kt < 4; ++kt) {
        float p0 = __builtin_amdgcn_exp2f(sv[kt][0]);
        float p1 = __builtin_amdgcn_exp2f(sv[kt][1]);
        float p2 = __builtin_amdgcn_exp2f(sv[kt][2]);
        float p3 = __builtin_amdgcn_exp2f(sv[kt][3]);
        w[kt][0] = cvt_pk_bf16(p0, p1);
        w[kt][1] = cvt_pk_bf16(p2, p3);
      }
      // in-register transpose: (kt0 <-> lane bit5), then (lane bit5 old <-> lane bit4)
      u32 pa[2][4];
#pragma unroll
      for (int kt1 = 0; kt1 < 2; ++kt1) {
#pragma unroll
        for (int hh = 0; hh < 2; ++hh) {
          u32 X = w[2 * kt1][hh], Y = w[2 * kt1 + 1][hh];
          asm("v_permlane32_swap_b32 %0, %1" : "+v"(X), "+v"(Y));
          asm("v_permlane16_swap_b32 %0, %1" : "+v"(X), "+v"(Y));
          pa[kt1][hh] = X;       // j1=0 -> word j=hh
          pa[kt1][2 + hh] = Y;   // j1=1 -> word j=2+hh
        }
      }
      u32x4 a0 = {pa[0][0], pa[0][1], pa[0][2], pa[0][3]};
      u32x4 a1 = {pa[1][0], pa[1][1], pa[1][2], pa[1][3]};
      short8_t pf0 = __builtin_bit_cast(short8_t, a0);   // keys 0..31 of chunk
      short8_t pf1 = __builtin_bit_cast(short8_t, a1);   // keys 32..63 of chunk
      accq[qt][0] = __builtin_amdgcn_mfma_f32_16x16x32_bf16(pf0, V[0], accq[qt][0], 0, 0, 0);
      accq[qt][0] = __builtin_amdgcn_mfma_f32_16x16x32_bf16(pf1, V[1], accq[qt][0], 0, 0, 0);
      accq[qt][1] = __builtin_amdgcn_mfma_f32_16x16x32_bf16(pf0, V[2], accq[qt][1], 0, 0, 0);
      accq[qt][1] = __builtin_amdgcn_mfma_f32_16x16x32_bf16(pf1, V[3], accq[qt][1], 0, 0, 0);
      acc_l[qt]   = __builtin_amdgcn_mfma_f32_16x16x32_bf16(pf0, ones, acc_l[qt], 0, 0, 0);
      acc_l[qt]   = __builtin_amdgcn_mfma_f32_16x16x32_bf16(pf1, ones, acc_l[qt], 0, 0, 0);
    }
    __builtin_amdgcn_s_setprio(0);
  };

  // prologue: chunk 0 -> A
  const u16* kp = Kb + seg_off(0);
  const u16* vp = Vb + seg_off(0);
  LOADK(KA, kp); LOADV(VA, vp);

  for (int cc = 0; cc < tot; cc += 2) {
    // pointers for chunk cc+1 (always valid: tot is a multiple of 16 >= 16, cc+1 < tot)
    const u16 *kp1, *vp1;
    if (((cc + 1) & 15) == 0) {
      size_t o = seg_off((cc + 1) >> 4);
      kp1 = Kb + o; vp1 = Vb + o;
    } else {
      kp1 = kp + 64 * ND; vp1 = vp + 64;
    }
    LOADK(KB, kp1); LOADV(VB, vp1);
    compute(KA, VA);

    // pointers for chunk cc+2 (guard table lookup at cc+2 == tot)
    const u16 *kp2, *vp2;
    if (((cc + 2) & 15) == 0) {
      if (cc + 2 < tot) { size_t o = seg_off((cc + 2) >> 4); kp2 = Kb + o; vp2 = Vb + o; }
      else { kp2 = kp1; vp2 = vp1; }
    } else {
      kp2 = kp1 + 64 * ND; vp2 = vp1 + 64;
    }
    if (cc + 2 < tot) { LOADK(KA, kp2); LOADV(VA, vp2); }
    compute(KB, VB);
    kp = kp2; vp = vp2;
  }
#undef LOADK
#undef LOADV

  // epilogue: acc_l[qt][r] already holds l for query 4g+r (broadcast over lm)
#pragma unroll
  for (int qt = 0; qt < 4; ++qt) {
#pragma unroll
    for (int r = 0; r < 4; ++r) {
      float inv = __builtin_amdgcn_rcpf(acc_l[qt][r]);
      int s = sbase + qt * 16 + 4 * g + r;
      u16* op = Ot + (size_t)(bt * NS + s) * NC + h * 32 + lm;
      op[0]  = f32_to_bf16(accq[qt][0][r] * inv);
      op[16] = f32_to_bf16(accq[qt][1][r] * inv);
    }
  }
}

// ------- output projection (LDS GEMM): out[bt][o][s] = Wo[m]·O^T + bo -------
__global__ __launch_bounds__(256, 3) void oproj_kernel(const u16* __restrict__ xdet,
                                                       const u16* __restrict__ Ot,
                                                       const u16* __restrict__ Wob,
                                                       const float* __restrict__ bo,
                                                       void* __restrict__ out) {
  __shared__ __align__(16) u16 As[128 * 32];
  __shared__ __align__(16) u16 Bs[128 * 32];
  bool isf = detect_isf(xdet);
  int bid = blockIdx.x;
  int bt = bid >> 4, rem = bid & 15;
  int obase = (rem & 1) * 128, s0 = (rem >> 1) * 128;
  int m = c_view_m[bt % NV];
  int tid = threadIdx.x;
  int wave = tid >> 6, lane = tid & 63, lm = lane & 15, g = lane >> 4;
  int wo = wave >> 1, ws = wave & 1;
  f32x4 acc[4][4];
  gemm128(Wob + (size_t)(m * NC + obase) * NC,
          Ot + ((size_t)bt * NS + s0) * NC, As, Bs, acc, wo, ws, lm, g, tid);
#pragma unroll
  for (int i = 0; i < 4; ++i) {
    int o_r0 = obase + wo * 64 + i * 16 + 4 * g;
    float4 bias = *(const float4*)&bo[m * NC + o_r0];
#pragma unroll
    for (int j = 0; j < 4; ++j) {
      int s = s0 + ws * 64 + j * 16 + lm;
      f32x4 c = acc[i][j];
      size_t base = (size_t)(bt * NC + o_r0) * NS + s;
      float v0 = c[0] + bias.x, v1 = c[1] + bias.y, v2 = c[2] + bias.z, v3 = c[3] + bias.w;
      if (isf) {
        float* fo = (float*)out;
        fo[base] = v0; fo[base + NS] = v1; fo[base + 2 * NS] = v2; fo[base + 3 * NS] = v3;
      } else {
        u16* ho = (u16*)out;
        ho[base] = f32_to_bf16(v0); ho[base + NS] = f32_to_bf16(v1);
        ho[base + 2 * NS] = f32_to_bf16(v2); ho[base + 3 * NS] = f32_to_bf16(v3);
      }
    }
  }
}

// ---------------- workspace layout (bytes) ----------------
// 0:        bq fp32 (15360)       -> 15360
// 15360:    bo fp32 (5120)        -> 20480
// 20480:    Wqkvb bf16 (1966080)  -> 1986560
// 1986560:  Wob bf16 (655360)     -> 2641920
// 2641920:  Xt bf16 (27262976)    -> 29904896
// 29904896: Qb bf16 (27262976)    -> 57167872
// 57167872: Kb bf16 (69206016)    -> 126373888   [pair][h][key][dim]
// 126373888:Vb bf16 (69206016)    -> 195579904   [pair][h][dim][key]  (pre-transposed)
// 195579904:Ot bf16 (27262976)    -> 222842880

extern "C" void kernel_launch(void* const* d_in, const int* in_sizes, int n_in,
                              void* d_out, int out_size, void* d_ws, size_t ws_size,
                              hipStream_t stream) {
  (void)in_sizes; (void)n_in; (void)out_size;
  const void* x     = d_in[0];
  const void* w_qkv = d_in[1];
  const void* b_qkv = d_in[2];
  const void* w_out = d_in[3];
  const void* b_out = d_in[4];

  if (ws_size < 222842880ull) return;

  char* wsb = (char*)d_ws;
  float* bq    = (float*)(wsb + 0);
  float* bo    = (float*)(wsb + 15360);
  u16*   Wqkvb = (u16*)(wsb + 20480);
  u16*   Wob   = (u16*)(wsb + 1986560);
  u16*   Xt    = (u16*)(wsb + 2641920);
  u16*   Qb    = (u16*)(wsb + 29904896);
  u16*   Kb    = (u16*)(wsb + 57167872);
  u16*   Vb    = (u16*)(wsb + 126373888);
  u16*   Ot    = (u16*)(wsb + 195579904);

  prep_w_kernel<<<5140, 256, 0, stream>>>((const u16*)x, w_qkv, w_out, b_qkv, b_out,
                                          Wqkvb, Wob, bq, bo);
  prep_x_kernel<<<dim3(52, 32, 8), 256, 0, stream>>>(x, Xt);
  qkvproj_kernel<<<5056, 256, 0, stream>>>(Xt, Wqkvb, bq, Qb, Kb, Vb);
  attn_kernel<<<1664, 256, 0, stream>>>(Qb, Kb, Vb, Ot);
  oproj_kernel<<<832, 256, 0, stream>>>((const u16*)x, Ot, Wob, bo, d_out);
}

// Round 10
// 542.238 us; speedup vs baseline: 1.6248x; 1.0145x over previous
//
#include <hip/hip_runtime.h>
#include <hip/hip_bf16.h>

#define NV 26
#define NS 1024
#define NC 256
#define NH 8
#define ND 32
#define NPAIR 66

typedef unsigned short u16;
typedef unsigned int u32;
typedef short short8_t __attribute__((ext_vector_type(8)));   // 8 bf16 MFMA frag
typedef float f32x4 __attribute__((ext_vector_type(4)));      // MFMA accumulator
typedef unsigned int u32x4 __attribute__((ext_vector_type(4)));

// ---------------- static routing tables (from _angle_select / _mha_index) ----------------
__constant__ int c_view_m[NV]  = {0,1,2,2,2,2,2,2,2,2,3,3,3,3,3,3,3,3,4,4,4,4,4,4,4,4};
__constant__ int c_view_nk[NV] = {4,4,4,3,4,3,4,3,4,3,4,4,4,4,4,4,4,4,4,3,4,3,4,3,4,3};
__constant__ int c_view_kv[NV][4] = {
  {0,1,2,3},      {4,5,6,7},      {8,10,16,17},   {9,11,18,-1},
  {8,10,12,19},   {11,13,20,-1},  {8,12,14,21},   {13,15,22,-1},
  {8,14,16,23},   {9,15,24,-1},   {25,34,40,41},  {26,33,35,42},
  {27,34,36,43},  {28,35,37,44},  {29,36,38,45},  {30,37,39,46},
  {31,38,40,47},  {32,33,39,48},  {49,50,59,65},  {51,58,60,-1},
  {49,52,59,61},  {53,60,62,-1},  {49,54,61,63},  {55,62,64,-1},
  {49,56,63,65},  {57,58,64,-1}
};
__constant__ int c_pair_m[NPAIR] = {
  0,0,0,0, 1,1,1,1,
  2,2,2,2,2,2,2,2,2,2,2,2,2,2,2,2,2,
  3,3,3,3,3,3,3,3,3,3,3,3,3,3,3,3,3,3,3,3,3,3,3,3,
  4,4,4,4,4,4,4,4,4,4,4,4,4,4,4,4,4
};
__constant__ int c_pair_j[NPAIR] = {
  18,20,22,24, 2,4,6,8,
  1,2,3,4,5,6,7,8,9,10,11,12,13,14,15,16,17,
  2,3,4,5,6,7,8,9,10,11,12,13,14,15,16,17,18,19,20,21,22,23,24,25,
  0,10,11,12,13,14,15,16,17,18,19,20,21,22,23,24,25
};

__device__ __forceinline__ float bf16_to_f32(u16 u) {
  return __uint_as_float(((u32)u) << 16);
}
__device__ __forceinline__ u16 f32_to_bf16(float f) {   // RNE
  u32 u = __float_as_uint(f);
  u32 r = (u + 0x7fffu + ((u >> 16) & 1u)) >> 16;
  return (u16)r;
}
__device__ __forceinline__ float ld_src(const void* p, size_t i, bool isf) {
  return isf ? ((const float*)p)[i] : bf16_to_f32(((const u16*)p)[i]);
}
// single-instruction packed f32x2 -> bf16x2 (RNE); guarantees no SW-RNE expansion
__device__ __forceinline__ u32 cvt_pk_bf16(float a, float b) {
  u32 r;
  asm("v_cvt_pk_bf16_f32 %0, %1, %2" : "=v"(r) : "v"(a), "v"(b));
  return r;
}
// dtype probe: fp32 tensors reinterpreted as bf16 halves blow past 1e6 almost surely
// over 64 samples (low halves have uniform-random exponent bits). Wave-uniform result.
__device__ __forceinline__ bool detect_isf(const u16* __restrict__ x) {
  float f = fabsf(bf16_to_f32(x[threadIdx.x & 63]));
  if (!(f < 3.0e38f)) f = 3.0e38f;
#pragma unroll
  for (int m = 1; m < 64; m <<= 1) f = fmaxf(f, __shfl_xor(f, m));
  return f > 1.0e6f;
}

// ------- prep_w: W -> bf16 (keep [o][c] layout = MFMA A-operand), biases -> fp32 -------
#define NW1 983040
#define NW2 327680
#define NB1 3840
#define NB2 1280
__global__ __launch_bounds__(256) void prep_w_kernel(const u16* __restrict__ xdet,
                                                     const void* __restrict__ w_qkv,
                                                     const void* __restrict__ w_out,
                                                     const void* __restrict__ b_qkv,
                                                     const void* __restrict__ b_out,
                                                     u16* __restrict__ Wqkvb, u16* __restrict__ Wob,
                                                     float* __restrict__ bq, float* __restrict__ bo) {
  bool isf = detect_isf(xdet);
  int i = blockIdx.x * 256 + threadIdx.x;
  if (i < NW1) Wqkvb[i] = f32_to_bf16(ld_src(w_qkv, i, isf));
  else if (i < NW1 + NW2) Wob[i - NW1] = f32_to_bf16(ld_src(w_out, i - NW1, isf));
  else if (i < NW1 + NW2 + NB1) bq[i - NW1 - NW2] = ld_src(b_qkv, i - NW1 - NW2, isf);
  else if (i < NW1 + NW2 + NB1 + NB2) bo[i - NW1 - NW2 - NB1] = ld_src(b_out, i - NW1 - NW2 - NB1, isf);
}

// ------- prep_x: x[bt][c][s] -> Xt[bt][s][c] bf16 (MFMA B-operand layout) -------
__global__ __launch_bounds__(256) void prep_x_kernel(const void* __restrict__ xin,
                                                     u16* __restrict__ Xt) {
  __shared__ float tile[32][33];
  bool isf = detect_isf((const u16*)xin);
  int bt = blockIdx.x;
  int s0 = blockIdx.y * 32, c0 = blockIdx.z * 32;
  int tid = threadIdx.x;
#pragma unroll
  for (int p = 0; p < 4; ++p) {
    int cl = (tid >> 5) + p * 8, sl = tid & 31;
    tile[cl][sl] = ld_src(xin, (size_t)(bt * NC + c0 + cl) * NS + s0 + sl, isf);
  }
  __syncthreads();
  int srow = tid >> 3, c4 = (tid & 7) * 4;
  ushort4 v;
  v.x = f32_to_bf16(tile[c4 + 0][srow]);
  v.y = f32_to_bf16(tile[c4 + 1][srow]);
  v.z = f32_to_bf16(tile[c4 + 2][srow]);
  v.w = f32_to_bf16(tile[c4 + 3][srow]);
  *(ushort4*)&Xt[(size_t)(bt * NS + s0 + srow) * NC + c0 + c4] = v;
}

// ------- LDS-staged GEMM tile: 128 o x 128 s, K=256, reg-prefetch pipeline -------
__device__ __forceinline__ void gemm128(const u16* __restrict__ A, const u16* __restrict__ B,
                                        u16* As, u16* Bs, f32x4 acc[4][4],
                                        int wo, int ws, int lm, int g, int tid) {
#pragma unroll
  for (int i = 0; i < 4; ++i)
#pragma unroll
    for (int j = 0; j < 4; ++j)
#pragma unroll
      for (int r = 0; r < 4; ++r) acc[i][j][r] = 0.f;
  int c0i = tid, c1i = tid + 256;
  const u16* a0p = A + (c0i >> 2) * NC + (c0i & 3) * 8;
  const u16* a1p = A + (c1i >> 2) * NC + (c1i & 3) * 8;
  const u16* b0p = B + (c0i >> 2) * NC + (c0i & 3) * 8;
  const u16* b1p = B + (c1i >> 2) * NC + (c1i & 3) * 8;
  uint4 ra0 = *(const uint4*)(a0p);
  uint4 ra1 = *(const uint4*)(a1p);
  uint4 rb0 = *(const uint4*)(b0p);
  uint4 rb1 = *(const uint4*)(b1p);
  const u16* arow = As + (wo * 64 + lm) * 32 + g * 8;
  const u16* brow = Bs + (ws * 64 + lm) * 32 + g * 8;
#pragma unroll
  for (int k0 = 0; k0 < NC; k0 += 32) {
    __syncthreads();
    *(uint4*)&As[c0i * 8] = ra0;
    *(uint4*)&As[c1i * 8] = ra1;
    *(uint4*)&Bs[c0i * 8] = rb0;
    *(uint4*)&Bs[c1i * 8] = rb1;
    if (k0 + 32 < NC) {
      ra0 = *(const uint4*)(a0p + k0 + 32);
      ra1 = *(const uint4*)(a1p + k0 + 32);
      rb0 = *(const uint4*)(b0p + k0 + 32);
      rb1 = *(const uint4*)(b1p + k0 + 32);
    }
    __syncthreads();
    short8_t af[4], bf[4];
#pragma unroll
    for (int i = 0; i < 4; ++i) af[i] = *(const short8_t*)(arow + i * 16 * 32);
#pragma unroll
    for (int j = 0; j < 4; ++j) bf[j] = *(const short8_t*)(brow + j * 16 * 32);
#pragma unroll
    for (int i = 0; i < 4; ++i)
#pragma unroll
      for (int j = 0; j < 4; ++j)
        acc[i][j] = __builtin_amdgcn_mfma_f32_16x16x32_bf16(af[i], bf[j], acc[i][j], 0, 0, 0);
  }
}

// ------- fused QKV projection: q jobs (blocks 0..831) then kv jobs (832..5055) -------
// K written [pair][h][key][dim]; V written TRANSPOSED [pair][h][dim][key] so the
// attention kernel can read V^T fragments straight from global (no LDS staging).
__global__ __launch_bounds__(256, 3) void qkvproj_kernel(const u16* __restrict__ Xt,
                                                         const u16* __restrict__ Wqkvb,
                                                         const float* __restrict__ bq,
                                                         u16* __restrict__ Qb,
                                                         u16* __restrict__ Kb,
                                                         u16* __restrict__ Vb) {
  __shared__ __align__(16) u16 As[128 * 32];
  __shared__ __align__(16) u16 Bs[128 * 32];
  int bid = blockIdx.x;
  int tid = threadIdx.x;
  int wave = tid >> 6, lane = tid & 63, lm = lane & 15, g = lane >> 4;
  int wo = wave >> 1, ws = wave & 1;

  int obase, s0, m, src_bt;
  u16* dst; int dslot; float sc; bool isV = false;
  if (bid < 832) {
    int bt = bid >> 4, rem = bid & 15;
    obase = (rem & 1) * 128; s0 = (rem >> 1) * 128;
    m = c_view_m[bt % NV]; src_bt = bt;
    dst = Qb; dslot = bt; sc = 0.25505653862161186f;
  } else {
    int jb = bid - 832;
    int pb = jb >> 5, rem = jb & 31;
    int ot = rem & 3; s0 = (rem >> 2) * 128;
    obase = 256 + ot * 128;
    m = c_pair_m[pb >> 1]; src_bt = (pb & 1) * NV + c_pair_j[pb >> 1];
    dst = (ot < 2) ? Kb : Vb; dslot = pb; sc = 1.0f;
    isV = (ot >= 2);
  }
  f32x4 acc[4][4];
  gemm128(Wqkvb + (size_t)(m * 768 + obase) * NC,
          Xt + ((size_t)src_bt * NS + s0) * NC, As, Bs, acc, wo, ws, lm, g, tid);
  int osub = (obase < 256) ? 0 : ((obase < 512) ? 256 : 512);
#pragma unroll
  for (int i = 0; i < 4; ++i) {
    int o_r0 = obase + wo * 64 + i * 16 + 4 * g;
    float4 bias = *(const float4*)&bq[m * 768 + o_r0];
    int oloc = o_r0 - osub;
    int h = oloc >> 5, d0 = oloc & 31;
#pragma unroll
    for (int j = 0; j < 4; ++j) {
      int s = s0 + ws * 64 + j * 16 + lm;
      f32x4 c = acc[i][j];
      ushort4 v;
      v.x = f32_to_bf16((c[0] + bias.x) * sc);
      v.y = f32_to_bf16((c[1] + bias.y) * sc);
      v.z = f32_to_bf16((c[2] + bias.z) * sc);
      v.w = f32_to_bf16((c[3] + bias.w) * sc);
      if (isV) {
        // V^T layout: [pair][h][d][key]; 4 consecutive dims -> 4 strided u16 stores
        u16* vt = dst + ((size_t)(dslot * NH + h) * ND + d0) * NS + s;
        vt[0]      = v.x;
        vt[NS]     = v.y;
        vt[2 * NS] = v.z;
        vt[3 * NS] = v.w;
      } else {
        *(ushort4*)&dst[((size_t)(dslot * NH + h) * NS + s) * ND + d0] = v;
      }
    }
  }
}

// ---------------- MFMA flash attention: in-register softmax/transpose + K/V reg prefetch -------
// Zero LDS, zero barriers. XCD-aware grid swizzle (R5: FETCH 406->85MB -> K/V are L2 hits).
// R10 = R9 with ONE setprio fence pair per 2-chunk iteration instead of one per chunk:
// setprio builtins are scheduling fences; at the measured ~2 waves/SIMD the per-chunk
// fences serialized each chunk's QK->exp2->permlane->PV dependency chain. Wrapping both
// computes in one region (cc+2 prefetch issued between them, after KA/VA's last read)
// lets the compiler overlap chunk B's QK/exp2 head with chunk A's PV tail.
// Fences still bracket every iteration (R7's total removal corrupted; this keeps them).
__global__ __launch_bounds__(256, 3) void attn_kernel(const u16* __restrict__ Qb,
                                                      const u16* __restrict__ Kb,
                                                      const u16* __restrict__ Vb,
                                                      u16* __restrict__ Ot) {
  int gid = blockIdx.x;
  int grp = (gid >> 5) * 8 + (gid & 7);   // bt*8 + h
  int z = (gid >> 3) & 3;
  int bt = grp >> 3;
  int h = grp & 7;
  int view = bt % NV;
  int b = bt / NV;
  int tid = threadIdx.x;
  int wave = tid >> 6, lane = tid & 63;
  int lm = lane & 15, g = lane >> 4;
  int sbase = z * 256 + wave * 64;
  int nk = c_view_nk[view];

  short8_t qf[4];
  {
    const u16* qrow = Qb + ((size_t)(bt * NH + h) * NS + sbase) * ND;
#pragma unroll
    for (int qt = 0; qt < 4; ++qt)
      qf[qt] = *(const short8_t*)(qrow + (qt * 16 + lm) * ND + g * 8);
  }
  f32x4 accq[4][2];
  f32x4 acc_l[4];
#pragma unroll
  for (int qt = 0; qt < 4; ++qt) {
#pragma unroll
    for (int r = 0; r < 4; ++r) { accq[qt][0][r] = 0.f; accq[qt][1][r] = 0.f; acc_l[qt][r] = 0.f; }
  }
  short8_t ones;
#pragma unroll
  for (int e = 0; e < 8; ++e) ones[e] = (short)0x3F80;   // bf16 1.0

  int tot = nk * 16;

  // loop-invariant lane offsets (u16 units)
  const int kvo  = lm * ND + g * 8;          // K: row lm, dwords g*8; kt via +kt*16*ND
  const int vvo0 = lm * NS + g * 8;          // V^T nt=0
  const int vvo1 = (16 + lm) * NS + g * 8;   // V^T nt=1

  // segment base for pair index nn (wave-uniform)
  auto seg_off = [&](int nn) -> size_t {
    int kvp = c_view_kv[view][nn];
    return (size_t)((kvp * 2 + b) * NH + h) * NS * ND;
  };

  short8_t KA[4], VA[4], KB[4], VB[4];

#define LOADK(DST, KP)                                                        \
  {                                                                           \
    _Pragma("unroll")                                                         \
    for (int kt = 0; kt < 4; ++kt)                                            \
      DST[kt] = *(const short8_t*)((KP) + kt * 16 * ND + kvo);                \
  }
#define LOADV(DST, VP)                                                        \
  {                                                                           \
    DST[0] = *(const short8_t*)((VP) + vvo0);                                 \
    DST[1] = *(const short8_t*)((VP) + vvo0 + 32);                            \
    DST[2] = *(const short8_t*)((VP) + vvo1);                                 \
    DST[3] = *(const short8_t*)((VP) + vvo1 + 32);                            \
  }

  // compute one 64-key chunk from register fragments K[4], V[4(nt*2+k2)]; no fences inside
  auto compute = [&](const short8_t (&K)[4], const short8_t (&V)[4]) {
#pragma unroll
    for (int qt = 0; qt < 4; ++qt) {
      f32x4 z4 = {0.f, 0.f, 0.f, 0.f};
      f32x4 sv[4];
#pragma unroll
      for (int kt = 0; kt < 4; ++kt)
        sv[kt] = __builtin_amdgcn_mfma_f32_16x16x32_bf16(K[kt], qf[qt], z4, 0, 0, 0);
      u32 w[4][2];
#pragma unroll
      for (int kt = 0; kt < 4; ++kt) {
        float p0 = __builtin_amdgcn_exp2f(sv[kt][0]);
        float p1 = __builtin_amdgcn_exp2f(sv[kt][1]);
        float p2 = __builtin_amdgcn_exp2f(sv[kt][2]);
        float p3 = __builtin_amdgcn_exp2f(sv[kt][3]);
        w[kt][0] = cvt_pk_bf16(p0, p1);
        w[kt][1] = cvt_pk_bf16(p2, p3);
      }
      // in-register transpose: (kt0 <-> lane bit5), then (lane bit5 old <-> lane bit4)
      u32 pa[2][4];
#pragma unroll
      for (int kt1 = 0; kt1 < 2; ++kt1) {
#pragma unroll
        for (int hh = 0; hh < 2; ++hh) {
          u32 X = w[2 * kt1][hh], Y = w[2 * kt1 + 1][hh];
          asm("v_permlane32_swap_b32 %0, %1" : "+v"(X), "+v"(Y));
          asm("v_permlane16_swap_b32 %0, %1" : "+v"(X), "+v"(Y));
          pa[kt1][hh] = X;       // j1=0 -> word j=hh
          pa[kt1][2 + hh] = Y;   // j1=1 -> word j=2+hh
        }
      }
      u32x4 a0 = {pa[0][0], pa[0][1], pa[0][2], pa[0][3]};
      u32x4 a1 = {pa[1][0], pa[1][1], pa[1][2], pa[1][3]};
      short8_t pf0 = __builtin_bit_cast(short8_t, a0);   // keys 0..31 of chunk
      short8_t pf1 = __builtin_bit_cast(short8_t, a1);   // keys 32..63 of chunk
      accq[qt][0] = __builtin_amdgcn_mfma_f32_16x16x32_bf16(pf0, V[0], accq[qt][0], 0, 0, 0);
      accq[qt][0] = __builtin_amdgcn_mfma_f32_16x16x32_bf16(pf1, V[1], accq[qt][0], 0, 0, 0);
      accq[qt][1] = __builtin_amdgcn_mfma_f32_16x16x32_bf16(pf0, V[2], accq[qt][1], 0, 0, 0);
      accq[qt][1] = __builtin_amdgcn_mfma_f32_16x16x32_bf16(pf1, V[3], accq[qt][1], 0, 0, 0);
      acc_l[qt]   = __builtin_amdgcn_mfma_f32_16x16x32_bf16(pf0, ones, acc_l[qt], 0, 0, 0);
      acc_l[qt]   = __builtin_amdgcn_mfma_f32_16x16x32_bf16(pf1, ones, acc_l[qt], 0, 0, 0);
    }
  };

  // prologue: chunk 0 -> A
  const u16* kp = Kb + seg_off(0);
  const u16* vp = Vb + seg_off(0);
  LOADK(KA, kp); LOADV(VA, vp);

  for (int cc = 0; cc < tot; cc += 2) {
    // pointers for chunk cc+1 (always valid: tot is a multiple of 16 >= 16, cc+1 < tot)
    const u16 *kp1, *vp1;
    if (((cc + 1) & 15) == 0) {
      size_t o = seg_off((cc + 1) >> 4);
      kp1 = Kb + o; vp1 = Vb + o;
    } else {
      kp1 = kp + 64 * ND; vp1 = vp + 64;
    }
    LOADK(KB, kp1); LOADV(VB, vp1);

    // pointers for chunk cc+2 (guard table lookup at cc+2 == tot)
    const u16 *kp2, *vp2;
    if (((cc + 2) & 15) == 0) {
      if (cc + 2 < tot) { size_t o = seg_off((cc + 2) >> 4); kp2 = Kb + o; vp2 = Vb + o; }
      else { kp2 = kp1; vp2 = vp1; }
    } else {
      kp2 = kp1 + 64 * ND; vp2 = vp1 + 64;
    }

    __builtin_amdgcn_s_setprio(1);
    compute(KA, VA);
    if (cc + 2 < tot) { LOADK(KA, kp2); LOADV(VA, vp2); }   // issue under compute(KB)
    compute(KB, VB);
    __builtin_amdgcn_s_setprio(0);
    kp = kp2; vp = vp2;
  }
#undef LOADK
#undef LOADV

  // epilogue: acc_l[qt][r] already holds l for query 4g+r (broadcast over lm)
#pragma unroll
  for (int qt = 0; qt < 4; ++qt) {
#pragma unroll
    for (int r = 0; r < 4; ++r) {
      float inv = __builtin_amdgcn_rcpf(acc_l[qt][r]);
      int s = sbase + qt * 16 + 4 * g + r;
      u16* op = Ot + (size_t)(bt * NS + s) * NC + h * 32 + lm;
      op[0]  = f32_to_bf16(accq[qt][0][r] * inv);
      op[16] = f32_to_bf16(accq[qt][1][r] * inv);
    }
  }
}

// ------- output projection (LDS GEMM): out[bt][o][s] = Wo[m]·O^T + bo -------
__global__ __launch_bounds__(256, 3) void oproj_kernel(const u16* __restrict__ xdet,
                                                       const u16* __restrict__ Ot,
                                                       const u16* __restrict__ Wob,
                                                       const float* __restrict__ bo,
                                                       void* __restrict__ out) {
  __shared__ __align__(16) u16 As[128 * 32];
  __shared__ __align__(16) u16 Bs[128 * 32];
  bool isf = detect_isf(xdet);
  int bid = blockIdx.x;
  int bt = bid >> 4, rem = bid & 15;
  int obase = (rem & 1) * 128, s0 = (rem >> 1) * 128;
  int m = c_view_m[bt % NV];
  int tid = threadIdx.x;
  int wave = tid >> 6, lane = tid & 63, lm = lane & 15, g = lane >> 4;
  int wo = wave >> 1, ws = wave & 1;
  f32x4 acc[4][4];
  gemm128(Wob + (size_t)(m * NC + obase) * NC,
          Ot + ((size_t)bt * NS + s0) * NC, As, Bs, acc, wo, ws, lm, g, tid);
#pragma unroll
  for (int i = 0; i < 4; ++i) {
    int o_r0 = obase + wo * 64 + i * 16 + 4 * g;
    float4 bias = *(const float4*)&bo[m * NC + o_r0];
#pragma unroll
    for (int j = 0; j < 4; ++j) {
      int s = s0 + ws * 64 + j * 16 + lm;
      f32x4 c = acc[i][j];
      size_t base = (size_t)(bt * NC + o_r0) * NS + s;
      float v0 = c[0] + bias.x, v1 = c[1] + bias.y, v2 = c[2] + bias.z, v3 = c[3] + bias.w;
      if (isf) {
        float* fo = (float*)out;
        fo[base] = v0; fo[base + NS] = v1; fo[base + 2 * NS] = v2; fo[base + 3 * NS] = v3;
      } else {
        u16* ho = (u16*)out;
        ho[base] = f32_to_bf16(v0); ho[base + NS] = f32_to_bf16(v1);
        ho[base + 2 * NS] = f32_to_bf16(v2); ho[base + 3 * NS] = f32_to_bf16(v3);
      }
    }
  }
}

// ---------------- workspace layout (bytes) ----------------
// 0:        bq fp32 (15360)       -> 15360
// 15360:    bo fp32 (5120)        -> 20480
// 20480:    Wqkvb bf16 (1966080)  -> 1986560
// 1986560:  Wob bf16 (655360)     -> 2641920
// 2641920:  Xt bf16 (27262976)    -> 29904896
// 29904896: Qb bf16 (27262976)    -> 57167872
// 57167872: Kb bf16 (69206016)    -> 126373888   [pair][h][key][dim]
// 126373888:Vb bf16 (69206016)    -> 195579904   [pair][h][dim][key]  (pre-transposed)
// 195579904:Ot bf16 (27262976)    -> 222842880

extern "C" void kernel_launch(void* const* d_in, const int* in_sizes, int n_in,
                              void* d_out, int out_size, void* d_ws, size_t ws_size,
                              hipStream_t stream) {
  (void)in_sizes; (void)n_in; (void)out_size;
  const void* x     = d_in[0];
  const void* w_qkv = d_in[1];
  const void* b_qkv = d_in[2];
  const void* w_out = d_in[3];
  const void* b_out = d_in[4];

  if (ws_size < 222842880ull) return;

  char* wsb = (char*)d_ws;
  float* bq    = (float*)(wsb + 0);
  float* bo    = (float*)(wsb + 15360);
  u16*   Wqkvb = (u16*)(wsb + 20480);
  u16*   Wob   = (u16*)(wsb + 1986560);
  u16*   Xt    = (u16*)(wsb + 2641920);
  u16*   Qb    = (u16*)(wsb + 29904896);
  u16*   Kb    = (u16*)(wsb + 57167872);
  u16*   Vb    = (u16*)(wsb + 126373888);
  u16*   Ot    = (u16*)(wsb + 195579904);

  prep_w_kernel<<<5140, 256, 0, stream>>>((const u16*)x, w_qkv, w_out, b_qkv, b_out,
                                          Wqkvb, Wob, bq, bo);
  prep_x_kernel<<<dim3(52, 32, 8), 256, 0, stream>>>(x, Xt);
  qkvproj_kernel<<<5056, 256, 0, stream>>>(Xt, Wqkvb, bq, Qb, Kb, Vb);
  attn_kernel<<<1664, 256, 0, stream>>>(Qb, Kb, Vb, Ot);
  oproj_kernel<<<832, 256, 0, stream>>>((const u16*)x, Ot, Wob, bo, d_out);
}